// Round 1
// baseline (3301.353 us; speedup 1.0000x reference)
//
#include <hip/hip_runtime.h>
#include <math.h>

// Problem constants (fixed by the reference)
#define BB 16
#define TT 2000
#define DENC 512
#define VV 1024
#define EE 256
#define HH 2
#define PP 640
#define MM (BB * TT)   // 32000 rows

// ---------------------------------------------------------------------------
// 1) Viterbi context: c[0]=0; c[t] = targets[t-1]!=0 ? targets[t-1] : c[t-1]
//    ctx0[b,t] = c[t]; ctx1[b,t] = c[t-1] (0 at t=0)
// ---------------------------------------------------------------------------
__global__ void ctx_kernel(const int* __restrict__ targets,
                           int* __restrict__ ctx0, int* __restrict__ ctx1) {
    __shared__ int tg[TT];
    __shared__ int cc[TT];
    const int b = blockIdx.x;
    const int* row = targets + b * TT;
    for (int t = threadIdx.x; t < TT; t += blockDim.x) tg[t] = row[t];
    __syncthreads();
    if (threadIdx.x == 0) {
        int cur = 0;
        for (int t = 0; t < TT; ++t) {
            cc[t] = cur;
            int v = tg[t];
            cur = (v != 0) ? v : cur;
        }
    }
    __syncthreads();
    for (int t = threadIdx.x; t < TT; t += blockDim.x) {
        ctx0[b * TT + t] = cc[t];
        ctx1[b * TT + t] = (t >= 1) ? cc[t - 1] : 0;
    }
}

// ---------------------------------------------------------------------------
// 2) fp32 tiled GEMM: C = act(Ain @ W + bias), Ain is one of:
//    - plain A [M,K]                         (GATHER=0, ADD2=0)
//    - A + A2 elementwise [M,K]              (ADD2=1)   (joint: enc+pred)
//    - gathered embeddings via ctx0/ctx1     (GATHER=1) (predictor input)
//    BM=BN=64, BK=16, 256 threads, 4x4 accum per thread.
//    Requires M%64==0, N%64==0, K%16==0 (true for all 6 calls).
// ---------------------------------------------------------------------------
#define BKK 16

template<bool TANH, bool ADD2, bool GATHER>
__global__ __launch_bounds__(256) void gemm_kernel(
    const float* __restrict__ A,      // [M,K]  (== emb when GATHER)
    const float* __restrict__ A2,     // [M,K]  (only when ADD2)
    const int*   __restrict__ ctx0,   // [M]    (only when GATHER)
    const int*   __restrict__ ctx1,   // [M]    (only when GATHER)
    const float* __restrict__ W,      // [K,N] row-major
    const float* __restrict__ bias,   // [N]
    float* __restrict__ C,            // [M,N]
    int M, int N, int K) {
    __shared__ __align__(16) float As[BKK][68];
    __shared__ __align__(16) float Bs[BKK][68];

    const int tid = threadIdx.x;
    const int rowBase = blockIdx.y * 64;
    const int colBase = blockIdx.x * 64;

    const int ar = tid >> 2;            // 0..63 : A-tile row
    const int ak = (tid & 3) << 2;      // 0,4,8,12 : A-tile k (float4)
    const int bk = tid >> 6;            // 0..3 : B-tile k base
    const int bn = tid & 63;            // 0..63 : B-tile col
    const int ty = tid >> 4;            // 0..15 : compute row group
    const int tx = tid & 15;            // 0..15 : compute col group

    float acc[4][4] = {{0.f,0.f,0.f,0.f},{0.f,0.f,0.f,0.f},
                       {0.f,0.f,0.f,0.f},{0.f,0.f,0.f,0.f}};

    const int arow = rowBase + ar;
    const float* Aptr  = GATHER ? nullptr : (A + (size_t)arow * K + ak);
    const float* A2ptr = ADD2 ? (A2 + (size_t)arow * K + ak) : nullptr;
    const float* Wptr  = W + (size_t)bk * N + colBase + bn;

    for (int k0 = 0; k0 < K; k0 += BKK) {
        // ---- A tile load (64 rows x 16 k), stored transposed in LDS ----
        float4 av4;
        if (GATHER) {
            const int kidx = k0 + ak;                 // 0..511, 4 elems stay in one half
            const int tok = (kidx < EE) ? ctx0[arow] : ctx1[arow];
            av4 = *(const float4*)(A + (size_t)tok * EE + (kidx & (EE - 1)));
        } else {
            av4 = *(const float4*)(Aptr + k0);
            if (ADD2) {
                float4 a2 = *(const float4*)(A2ptr + k0);
                av4.x += a2.x; av4.y += a2.y; av4.z += a2.z; av4.w += a2.w;
            }
        }
        As[ak + 0][ar] = av4.x;
        As[ak + 1][ar] = av4.y;
        As[ak + 2][ar] = av4.z;
        As[ak + 3][ar] = av4.w;

        // ---- B tile load (16 k x 64 cols), coalesced ----
        #pragma unroll
        for (int i = 0; i < 4; ++i)
            Bs[bk + 4 * i][bn] = Wptr[(size_t)(k0 + 4 * i) * N];

        __syncthreads();

        // ---- compute ----
        #pragma unroll
        for (int kk = 0; kk < BKK; ++kk) {
            float4 a4 = *(const float4*)&As[kk][ty * 4];
            float4 b4 = *(const float4*)&Bs[kk][tx * 4];
            float av[4] = {a4.x, a4.y, a4.z, a4.w};
            float bv[4] = {b4.x, b4.y, b4.z, b4.w};
            #pragma unroll
            for (int i = 0; i < 4; ++i)
                #pragma unroll
                for (int j = 0; j < 4; ++j)
                    acc[i][j] = fmaf(av[i], bv[j], acc[i][j]);
        }
        __syncthreads();
    }

    // ---- epilogue: +bias, optional tanh, float4 store ----
    float4 b4 = *(const float4*)(bias + colBase + tx * 4);
    #pragma unroll
    for (int i = 0; i < 4; ++i) {
        size_t r = (size_t)(rowBase + ty * 4 + i);
        float4 o;
        o.x = acc[i][0] + b4.x;
        o.y = acc[i][1] + b4.y;
        o.z = acc[i][2] + b4.z;
        o.w = acc[i][3] + b4.w;
        if (TANH) { o.x = tanhf(o.x); o.y = tanhf(o.y); o.z = tanhf(o.z); o.w = tanhf(o.w); }
        *(float4*)(C + r * N + colBase + tx * 4) = o;
    }
}

// ---------------------------------------------------------------------------
// 3) In-place log-softmax over rows of length 1024 (3*M rows back-to-back)
// ---------------------------------------------------------------------------
__global__ __launch_bounds__(256) void logsoftmax_kernel(float* __restrict__ x) {
    __shared__ float red[4];
    __shared__ float bres;
    const size_t base = (size_t)blockIdx.x * VV;
    const int t = threadIdx.x;

    float v[4];
    #pragma unroll
    for (int i = 0; i < 4; ++i) v[i] = x[base + t + 256 * i];

    float m = fmaxf(fmaxf(v[0], v[1]), fmaxf(v[2], v[3]));
    #pragma unroll
    for (int o = 32; o > 0; o >>= 1) m = fmaxf(m, __shfl_down(m, o, 64));
    if ((t & 63) == 0) red[t >> 6] = m;
    __syncthreads();
    if (t == 0) bres = fmaxf(fmaxf(red[0], red[1]), fmaxf(red[2], red[3]));
    __syncthreads();
    m = bres;

    float s = 0.f;
    #pragma unroll
    for (int i = 0; i < 4; ++i) s += expf(v[i] - m);
    #pragma unroll
    for (int o = 32; o > 0; o >>= 1) s += __shfl_down(s, o, 64);
    __syncthreads();
    if ((t & 63) == 0) red[t >> 6] = s;
    __syncthreads();
    if (t == 0) bres = logf(red[0] + red[1] + red[2] + red[3]);
    __syncthreads();
    const float lse = bres + m;

    #pragma unroll
    for (int i = 0; i < 4; ++i) x[base + t + 256 * i] = v[i] - lse;
}

// ---------------------------------------------------------------------------
// 4) enc_lens passthrough (output buffer is read back as fp32)
// ---------------------------------------------------------------------------
__global__ void lens_kernel(const int* __restrict__ features_len,
                            float* __restrict__ out_lens) {
    if (threadIdx.x < BB) out_lens[threadIdx.x] = (float)features_len[threadIdx.x];
}

// ---------------------------------------------------------------------------
extern "C" void kernel_launch(void* const* d_in, const int* in_sizes, int n_in,
                              void* d_out, int out_size, void* d_ws, size_t ws_size,
                              hipStream_t stream) {
    const float* encoder_out  = (const float*)d_in[0];
    const int*   features_len = (const int*)  d_in[1];
    const int*   targets      = (const int*)  d_in[2];
    const float* W_enc = (const float*)d_in[3];
    const float* b_enc = (const float*)d_in[4];
    const float* emb   = (const float*)d_in[5];
    const float* W_p1  = (const float*)d_in[6];
    const float* b_p1  = (const float*)d_in[7];
    const float* W_p2  = (const float*)d_in[8];
    const float* b_p2  = (const float*)d_in[9];
    const float* W_po  = (const float*)d_in[10];
    const float* b_po  = (const float*)d_in[11];
    const float* W_j1  = (const float*)d_in[12];
    const float* b_j1  = (const float*)d_in[13];
    const float* W_j2  = (const float*)d_in[14];
    const float* b_j2  = (const float*)d_in[15];

    float* out = (float*)d_out;
    const size_t BTV = (size_t)MM * VV;
    float* out_logits = out;             // log_probs      [B,T,V]
    float* out_pred   = out + BTV;       // pred_log_probs [B,T,V]
    float* out_enc    = out + 2 * BTV;   // enc_log_probs  [B,T,V]
    float* out_lens   = out + 3 * BTV;   // enc_lens       [B]

    // workspace layout (~157 MB)
    char* ws = (char*)d_ws;
    int*   ctx0 = (int*)ws;                                   // 128000 B
    int*   ctx1 = (int*)(ws + 128000);                        // 128000 B
    float* h1   = (float*)(ws + 256000);                      // 32000*640*4 = 81,920,000 B
    float* h2   = (float*)(ws + 256000 + 81920000);           // 81,920,000 B

    // 1) context
    ctx_kernel<<<BB, 256, 0, stream>>>(targets, ctx0, ctx1);

    // 2) encoder head: enc = encoder_out @ W_enc + b_enc  -> raw into out_enc
    gemm_kernel<false,false,false><<<dim3(VV/64, MM/64), 256, 0, stream>>>(
        encoder_out, nullptr, nullptr, nullptr, W_enc, b_enc, out_enc, MM, VV, DENC);

    // 3) predictor layer 1 (gathered embeddings): h1 = tanh(a @ W_p1 + b_p1)
    gemm_kernel<true,false,true><<<dim3(PP/64, MM/64), 256, 0, stream>>>(
        emb, nullptr, ctx0, ctx1, W_p1, b_p1, h1, MM, PP, HH*EE);

    // 4) predictor layer 2: h2 = tanh(h1 @ W_p2 + b_p2)
    gemm_kernel<true,false,false><<<dim3(PP/64, MM/64), 256, 0, stream>>>(
        h1, nullptr, nullptr, nullptr, W_p2, b_p2, h2, MM, PP, PP);

    // 5) predictor out: pred = h2 @ W_po + b_po  -> raw into out_pred
    gemm_kernel<false,false,false><<<dim3(VV/64, MM/64), 256, 0, stream>>>(
        h2, nullptr, nullptr, nullptr, W_po, b_po, out_pred, MM, VV, PP);

    // 6) joint hidden: hj = tanh((enc + pred) @ W_j1 + b_j1) -> h1 (reuse)
    gemm_kernel<true,true,false><<<dim3(PP/64, MM/64), 256, 0, stream>>>(
        out_enc, out_pred, nullptr, nullptr, W_j1, b_j1, h1, MM, PP, VV);

    // 7) joint out: logits = hj @ W_j2 + b_j2 -> raw into out_logits
    gemm_kernel<false,false,false><<<dim3(VV/64, MM/64), 256, 0, stream>>>(
        h1, nullptr, nullptr, nullptr, W_j2, b_j2, out_logits, MM, VV, PP);

    // 8) in-place log_softmax over all three [32000,1024] sections
    logsoftmax_kernel<<<3 * MM, 256, 0, stream>>>(out);

    // 9) enc_lens
    lens_kernel<<<1, 64, 0, stream>>>(features_len, out_lens);
}

// Round 2
// 1044.125 us; speedup vs baseline: 3.1618x; 3.1618x over previous
//
#include <hip/hip_runtime.h>
#include <math.h>

typedef unsigned short ushort_t;
typedef unsigned int uint_t;

// Problem constants (fixed by the reference)
#define BB 16
#define TT 2000
#define DENC 512
#define VV 1024
#define EE 256
#define PP 640
#define MM (BB * TT)   // 32000 rows

// MFMA fragment types (per cdna_hip_programming.md §3, compile-verified on gfx950)
typedef __attribute__((ext_vector_type(8))) short bf16x8;
typedef __attribute__((ext_vector_type(4))) float f32x4;

// ---------------------------------------------------------------------------
// helpers
// ---------------------------------------------------------------------------
__device__ __forceinline__ ushort_t f2bf(float x) {
    union { float f; uint_t u; } v; v.f = x;
    uint_t r = v.u + 0x7fffu + ((v.u >> 16) & 1u);   // RTNE
    return (ushort_t)(r >> 16);
}

__device__ __forceinline__ void async_ld16(const ushort_t* g, ushort_t* l) {
    __builtin_amdgcn_global_load_lds(
        (const __attribute__((address_space(1))) void*)g,
        (__attribute__((address_space(3))) void*)l, 16, 0, 0);
}

// ---------------------------------------------------------------------------
// 1) Viterbi context: c[0]=0; c[t] = targets[t-1]!=0 ? targets[t-1] : c[t-1]
// ---------------------------------------------------------------------------
__global__ void ctx_kernel(const int* __restrict__ targets,
                           int* __restrict__ ctx0, int* __restrict__ ctx1) {
    __shared__ int tg[TT];
    __shared__ int cc[TT];
    const int b = blockIdx.x;
    const int* row = targets + b * TT;
    for (int t = threadIdx.x; t < TT; t += blockDim.x) tg[t] = row[t];
    __syncthreads();
    if (threadIdx.x == 0) {
        int cur = 0;
        for (int t = 0; t < TT; ++t) {
            cc[t] = cur;
            int v = tg[t];
            cur = (v != 0) ? v : cur;
        }
    }
    __syncthreads();
    for (int t = threadIdx.x; t < TT; t += blockDim.x) {
        ctx0[b * TT + t] = cc[t];
        ctx1[b * TT + t] = (t >= 1) ? cc[t - 1] : 0;
    }
}

// ---------------------------------------------------------------------------
// 2) Weight transpose + fp32->bf16: W[K,N] -> WT[N,K] (bf16)
// ---------------------------------------------------------------------------
__global__ __launch_bounds__(256) void transpose_cvt_kernel(
    const float* __restrict__ W, ushort_t* __restrict__ WT, int K, int N) {
    __shared__ float t[32][33];
    const int n0 = blockIdx.x * 32, k0 = blockIdx.y * 32;
    const int tx = threadIdx.x, ty0 = threadIdx.y;  // blockDim (32,8)
    #pragma unroll
    for (int i = 0; i < 4; ++i) {
        int ty = ty0 + i * 8;
        t[ty][tx] = W[(size_t)(k0 + ty) * N + n0 + tx];
    }
    __syncthreads();
    #pragma unroll
    for (int i = 0; i < 4; ++i) {
        int ty = ty0 + i * 8;
        WT[(size_t)(n0 + ty) * K + k0 + tx] = f2bf(t[tx][ty]);
    }
}

// ---------------------------------------------------------------------------
// 3) fp32 -> bf16 elementwise (n % 4 == 0)
// ---------------------------------------------------------------------------
__global__ __launch_bounds__(256) void cvt_kernel(const float* __restrict__ in,
                                                  ushort_t* __restrict__ out, int n) {
    int i = (blockIdx.x * 256 + threadIdx.x) * 4;
    if (i >= n) return;
    float4 v = *(const float4*)(in + i);
    ushort_t o[4] = {f2bf(v.x), f2bf(v.y), f2bf(v.z), f2bf(v.w)};
    *(uint2*)(out + i) = *(uint2*)o;
}

// ---------------------------------------------------------------------------
// 4) add + fp32 -> bf16 (joint input = enc + pred)
// ---------------------------------------------------------------------------
__global__ __launch_bounds__(256) void add_cvt_kernel(const float* __restrict__ a,
                                                      const float* __restrict__ b,
                                                      ushort_t* __restrict__ out, int n) {
    int i = (blockIdx.x * 256 + threadIdx.x) * 4;
    if (i >= n) return;
    float4 x = *(const float4*)(a + i);
    float4 y = *(const float4*)(b + i);
    ushort_t o[4] = {f2bf(x.x + y.x), f2bf(x.y + y.y), f2bf(x.z + y.z), f2bf(x.w + y.w)};
    *(uint2*)(out + i) = *(uint2*)o;
}

// ---------------------------------------------------------------------------
// 5) gather predictor input: out[m, 0:256]=emb[ctx0[m]], out[m,256:512]=emb[ctx1[m]]
// ---------------------------------------------------------------------------
__global__ __launch_bounds__(256) void gather_kernel(const float* __restrict__ emb,
                                                     const int* __restrict__ ctx0,
                                                     const int* __restrict__ ctx1,
                                                     ushort_t* __restrict__ out) {
    const int m = blockIdx.x;
    const int t = threadIdx.x;
    const int c0 = ctx0[m], c1 = ctx1[m];
    out[(size_t)m * 512 + t]       = f2bf(emb[(size_t)c0 * EE + t]);
    out[(size_t)m * 512 + 256 + t] = f2bf(emb[(size_t)c1 * EE + t]);
}

// ---------------------------------------------------------------------------
// 6) bf16 MFMA GEMM (m97 structure): C = act(A @ BT^T + bias)
//    A [M,K] bf16 row-major, BT [N,K] bf16 row-major (pre-transposed weight)
//    128x128 tile, BK=32, 256 threads = 4 waves (2x2), 4x4 16x16x32 frags/wave
//    Requires M%128==0, N%128==0, K%32==0.
// ---------------------------------------------------------------------------
template<bool TANH, bool OUTBF>
__global__ __launch_bounds__(256) void gemm_bf16_kernel(
    const ushort_t* __restrict__ A, const ushort_t* __restrict__ BT,
    const float* __restrict__ bias, void* __restrict__ Cout,
    int M, int N, int K) {
    __shared__ __align__(16) ushort_t As[128 * 32];
    __shared__ __align__(16) ushort_t Bs[128 * 32];

    const int tid = threadIdx.x;
    const int wave = tid >> 6, lane = tid & 63;
    const int ln = lane & 15, quad = lane >> 4;
    const int wr = wave >> 1, wc = wave & 1;
    const int rowBase = blockIdx.y * 128;
    const int colBase = blockIdx.x * 128;

    // staging: issue s covers chunk = s*256 + wave*64 + lane (16B chunks)
    const int c0 = wave * 64 + lane;
    const int r0 = c0 >> 2, ko0 = (c0 & 3) * 8;
    const int c1 = 256 + c0;
    const int r1 = c1 >> 2, ko1 = (c1 & 3) * 8;
    const ushort_t* gA0 = A + (size_t)(rowBase + r0) * K + ko0;
    const ushort_t* gA1 = A + (size_t)(rowBase + r1) * K + ko1;
    const ushort_t* gB0 = BT + (size_t)(colBase + r0) * K + ko0;
    const ushort_t* gB1 = BT + (size_t)(colBase + r1) * K + ko1;
    ushort_t* lA0 = As + wave * 512;          // wave-uniform LDS dest bases
    ushort_t* lA1 = As + 2048 + wave * 512;
    ushort_t* lB0 = Bs + wave * 512;
    ushort_t* lB1 = Bs + 2048 + wave * 512;

    f32x4 acc[4][4] = {};

    for (int k0 = 0; k0 < K; k0 += 32) {
        async_ld16(gA0 + k0, lA0);
        async_ld16(gA1 + k0, lA1);
        async_ld16(gB0 + k0, lB0);
        async_ld16(gB1 + k0, lB1);
        __syncthreads();

        bf16x8 a[4], b[4];
        #pragma unroll
        for (int i = 0; i < 4; ++i)
            a[i] = *(const bf16x8*)&As[(wr * 64 + i * 16 + ln) * 32 + quad * 8];
        #pragma unroll
        for (int j = 0; j < 4; ++j)
            b[j] = *(const bf16x8*)&Bs[(wc * 64 + j * 16 + ln) * 32 + quad * 8];
        #pragma unroll
        for (int i = 0; i < 4; ++i)
            #pragma unroll
            for (int j = 0; j < 4; ++j)
                acc[i][j] = __builtin_amdgcn_mfma_f32_16x16x32_bf16(a[i], b[j], acc[i][j], 0, 0, 0);
        __syncthreads();
    }

    // epilogue: C/D layout col=lane&15, row=quad*4+reg  [m89/m91 verified]
    float bv[4];
    #pragma unroll
    for (int j = 0; j < 4; ++j) bv[j] = bias[colBase + wc * 64 + j * 16 + ln];

    #pragma unroll
    for (int i = 0; i < 4; ++i) {
        #pragma unroll
        for (int r = 0; r < 4; ++r) {
            const size_t row = (size_t)(rowBase + wr * 64 + i * 16 + quad * 4 + r);
            #pragma unroll
            for (int j = 0; j < 4; ++j) {
                const int col = colBase + wc * 64 + j * 16 + ln;
                float v = acc[i][j][r] + bv[j];
                if (TANH) v = tanhf(v);
                if (OUTBF) ((ushort_t*)Cout)[row * N + col] = f2bf(v);
                else       ((float*)Cout)[row * N + col] = v;
            }
        }
    }
}

// ---------------------------------------------------------------------------
// 7) In-place log-softmax over rows of length 1024 (3*M rows)
// ---------------------------------------------------------------------------
__global__ __launch_bounds__(256) void logsoftmax_kernel(float* __restrict__ x) {
    __shared__ float red[4];
    __shared__ float bres;
    const size_t base = (size_t)blockIdx.x * VV;
    const int t = threadIdx.x;

    float v[4];
    #pragma unroll
    for (int i = 0; i < 4; ++i) v[i] = x[base + t + 256 * i];

    float m = fmaxf(fmaxf(v[0], v[1]), fmaxf(v[2], v[3]));
    #pragma unroll
    for (int o = 32; o > 0; o >>= 1) m = fmaxf(m, __shfl_down(m, o, 64));
    if ((t & 63) == 0) red[t >> 6] = m;
    __syncthreads();
    if (t == 0) bres = fmaxf(fmaxf(red[0], red[1]), fmaxf(red[2], red[3]));
    __syncthreads();
    m = bres;

    float s = 0.f;
    #pragma unroll
    for (int i = 0; i < 4; ++i) s += expf(v[i] - m);
    #pragma unroll
    for (int o = 32; o > 0; o >>= 1) s += __shfl_down(s, o, 64);
    __syncthreads();
    if ((t & 63) == 0) red[t >> 6] = s;
    __syncthreads();
    if (t == 0) bres = logf(red[0] + red[1] + red[2] + red[3]);
    __syncthreads();
    const float lse = bres + m;

    #pragma unroll
    for (int i = 0; i < 4; ++i) x[base + t + 256 * i] = v[i] - lse;
}

// ---------------------------------------------------------------------------
// 8) enc_lens passthrough
// ---------------------------------------------------------------------------
__global__ void lens_kernel(const int* __restrict__ features_len,
                            float* __restrict__ out_lens) {
    if (threadIdx.x < BB) out_lens[threadIdx.x] = (float)features_len[threadIdx.x];
}

// ---------------------------------------------------------------------------
extern "C" void kernel_launch(void* const* d_in, const int* in_sizes, int n_in,
                              void* d_out, int out_size, void* d_ws, size_t ws_size,
                              hipStream_t stream) {
    const float* encoder_out  = (const float*)d_in[0];
    const int*   features_len = (const int*)  d_in[1];
    const int*   targets      = (const int*)  d_in[2];
    const float* W_enc = (const float*)d_in[3];
    const float* b_enc = (const float*)d_in[4];
    const float* emb   = (const float*)d_in[5];
    const float* W_p1  = (const float*)d_in[6];
    const float* b_p1  = (const float*)d_in[7];
    const float* W_p2  = (const float*)d_in[8];
    const float* b_p2  = (const float*)d_in[9];
    const float* W_po  = (const float*)d_in[10];
    const float* b_po  = (const float*)d_in[11];
    const float* W_j1  = (const float*)d_in[12];
    const float* b_j1  = (const float*)d_in[13];
    const float* W_j2  = (const float*)d_in[14];
    const float* b_j2  = (const float*)d_in[15];

    float* out = (float*)d_out;
    const size_t BTV = (size_t)MM * VV;
    float* out_logits = out;             // log_probs      [B,T,V]
    float* out_pred   = out + BTV;       // pred_log_probs [B,T,V]
    float* out_enc    = out + 2 * BTV;   // enc_log_probs  [B,T,V]
    float* out_lens   = out + 3 * BTV;   // enc_lens       [B]

    // ---- workspace layout (bytes), ~121 MB total ----
    char* ws = (char*)d_ws;
    int*      ctx0   = (int*)ws;                               // 128,000
    int*      ctx1   = (int*)(ws + 128000);                    // 128,000
    size_t off = 256000;
    ushort_t* WTenc = (ushort_t*)(ws + off); off += (size_t)VV * DENC * 2;  // 1,048,576
    ushort_t* WTp1  = (ushort_t*)(ws + off); off += (size_t)PP * DENC * 2;  //   655,360
    ushort_t* WTp2  = (ushort_t*)(ws + off); off += (size_t)PP * PP * 2;    //   819,200
    ushort_t* WTpo  = (ushort_t*)(ws + off); off += (size_t)VV * PP * 2;    // 1,310,720
    ushort_t* WTj1  = (ushort_t*)(ws + off); off += (size_t)PP * VV * 2;    // 1,310,720
    ushort_t* WTj2  = (ushort_t*)(ws + off); off += (size_t)VV * PP * 2;    // 1,310,720
    ushort_t* h1    = (ushort_t*)(ws + off); off += (size_t)MM * PP * 2;    // 40,960,000
    // region below is time-shared: {Abuf (gather / enc bf16), h2} then {sum}
    ushort_t* Abuf  = (ushort_t*)(ws + off);                                // 32,768,000
    ushort_t* h2    = (ushort_t*)(ws + off + (size_t)MM * DENC * 2);        // 40,960,000
    ushort_t* sumb  = Abuf;                                                 // 65,536,000 (aliases Abuf+h2)

    // 1) context
    ctx_kernel<<<BB, 256, 0, stream>>>(targets, ctx0, ctx1);

    // 2) weight transposes (fp32 -> bf16 [N,K])
    dim3 tcb(32, 8);
    transpose_cvt_kernel<<<dim3(VV/32, DENC/32), tcb, 0, stream>>>(W_enc, WTenc, DENC, VV);
    transpose_cvt_kernel<<<dim3(PP/32, DENC/32), tcb, 0, stream>>>(W_p1, WTp1, DENC, PP);
    transpose_cvt_kernel<<<dim3(PP/32, PP/32),   tcb, 0, stream>>>(W_p2, WTp2, PP, PP);
    transpose_cvt_kernel<<<dim3(VV/32, PP/32),   tcb, 0, stream>>>(W_po, WTpo, PP, VV);
    transpose_cvt_kernel<<<dim3(PP/32, VV/32),   tcb, 0, stream>>>(W_j1, WTj1, VV, PP);
    transpose_cvt_kernel<<<dim3(VV/32, PP/32),   tcb, 0, stream>>>(W_j2, WTj2, PP, VV);

    // 3) predictor input gather (bf16) -> Abuf, then predictor L1
    gather_kernel<<<MM, 256, 0, stream>>>(emb, ctx0, ctx1, Abuf);
    gemm_bf16_kernel<true, true><<<dim3(PP/128, MM/128), 256, 0, stream>>>(
        Abuf, WTp1, b_p1, h1, MM, PP, DENC);

    // 4) encoder head: cvt encoder_out -> Abuf (now free), GEMM -> out_enc (fp32 raw)
    cvt_kernel<<<(MM * DENC / 4 + 255) / 256, 256, 0, stream>>>(encoder_out, Abuf, MM * DENC);
    gemm_bf16_kernel<false, false><<<dim3(VV/128, MM/128), 256, 0, stream>>>(
        Abuf, WTenc, b_enc, out_enc, MM, VV, DENC);

    // 5) predictor L2: h2 = tanh(h1 @ W_p2 + b_p2) (bf16)
    gemm_bf16_kernel<true, true><<<dim3(PP/128, MM/128), 256, 0, stream>>>(
        h1, WTp2, b_p2, h2, MM, PP, PP);

    // 6) predictor out: pred = h2 @ W_po + b_po -> out_pred (fp32 raw)
    gemm_bf16_kernel<false, false><<<dim3(VV/128, MM/128), 256, 0, stream>>>(
        h2, WTpo, b_po, out_pred, MM, VV, PP);

    // 7) joint input: sum = bf16(enc + pred)  (Abuf/h2 both free now)
    add_cvt_kernel<<<(MM * VV / 4 + 255) / 256, 256, 0, stream>>>(
        out_enc, out_pred, sumb, MM * VV);

    // 8) joint hidden: hj = tanh(sum @ W_j1 + b_j1) -> h1 (reuse, bf16)
    gemm_bf16_kernel<true, true><<<dim3(PP/128, MM/128), 256, 0, stream>>>(
        sumb, WTj1, b_j1, h1, MM, PP, VV);

    // 9) joint out: logits = hj @ W_j2 + b_j2 -> out_logits (fp32 raw)
    gemm_bf16_kernel<false, false><<<dim3(VV/128, MM/128), 256, 0, stream>>>(
        h1, WTj2, b_j2, out_logits, MM, VV, PP);

    // 10) in-place log_softmax over all three [32000,1024] sections
    logsoftmax_kernel<<<3 * MM, 256, 0, stream>>>(out);

    // 11) enc_lens
    lens_kernel<<<1, 64, 0, stream>>>(features_len, out_lens);
}